// Round 2
// baseline (241.355 us; speedup 1.0000x reference)
//
#include <hip/hip_runtime.h>

#define THREADS 256
#define ITER    4                 // float4 per thread per array
#define BLOCKS  4096              // 4096*256*4 = 4,194,304 float4 = 16,777,216 floats
#define WAVES   (THREADS / 64)

// f(i) = log(v2) - log(v1) + v1/v2 + (mu2-mu1)^2/v2
//      = t - log(t) + d*d*r      with r = 1/v2, t = v1*r
__global__ __launch_bounds__(THREADS) void kl_partial_kernel(
    const float4* __restrict__ mu1, const float4* __restrict__ mu2,
    const float4* __restrict__ v1,  const float4* __restrict__ v2,
    float* __restrict__ partial, int n4)
{
    const int base = blockIdx.x * (THREADS * ITER) + threadIdx.x;

    float4 a[ITER], b[ITER], x1[ITER], x2[ITER];

    // Issue all 16 loads before any consumption -> max outstanding VMEM.
    #pragma unroll
    for (int j = 0; j < ITER; ++j) {
        const int i = base + j * THREADS;
        x2[j] = v2[i];
    }
    #pragma unroll
    for (int j = 0; j < ITER; ++j) {
        const int i = base + j * THREADS;
        x1[j] = v1[i];
    }
    #pragma unroll
    for (int j = 0; j < ITER; ++j) {
        const int i = base + j * THREADS;
        a[j] = mu1[i];
        b[j] = mu2[i];
    }

    float acc0 = 0.0f, acc1 = 0.0f;   // two chains to break serial dependence

    #pragma unroll
    for (int j = 0; j < ITER; ++j) {
        {
            float r = __builtin_amdgcn_rcpf(x2[j].x);
            float t = x1[j].x * r;
            float d = b[j].x - a[j].x;
            acc0 += (t - __logf(t)) + d * d * r;
        }
        {
            float r = __builtin_amdgcn_rcpf(x2[j].y);
            float t = x1[j].y * r;
            float d = b[j].y - a[j].y;
            acc1 += (t - __logf(t)) + d * d * r;
        }
        {
            float r = __builtin_amdgcn_rcpf(x2[j].z);
            float t = x1[j].z * r;
            float d = b[j].z - a[j].z;
            acc0 += (t - __logf(t)) + d * d * r;
        }
        {
            float r = __builtin_amdgcn_rcpf(x2[j].w);
            float t = x1[j].w * r;
            float d = b[j].w - a[j].w;
            acc1 += (t - __logf(t)) + d * d * r;
        }
    }

    float acc = acc0 + acc1;

    // wave-level reduce (64 lanes)
    #pragma unroll
    for (int off = 32; off > 0; off >>= 1)
        acc += __shfl_down(acc, off, 64);

    __shared__ float sm[WAVES];
    const int lane = threadIdx.x & 63;
    const int wave = threadIdx.x >> 6;
    if (lane == 0) sm[wave] = acc;
    __syncthreads();
    if (threadIdx.x == 0) {
        float s = 0.0f;
        #pragma unroll
        for (int w = 0; w < WAVES; ++w) s += sm[w];
        partial[blockIdx.x] = s;
    }
}

// Reduce per-block partials (double accumulation): out = 0.5*(S/B - N)
__global__ __launch_bounds__(THREADS) void kl_final_kernel(
    const float* __restrict__ partial, float* __restrict__ out,
    int nblocks, float invB, float nDim)
{
    double acc = 0.0;
    for (int i = threadIdx.x; i < nblocks; i += THREADS)
        acc += (double)partial[i];

    #pragma unroll
    for (int off = 32; off > 0; off >>= 1)
        acc += __shfl_down(acc, off, 64);

    __shared__ double sm[WAVES];
    const int lane = threadIdx.x & 63;
    const int wave = threadIdx.x >> 6;
    if (lane == 0) sm[wave] = acc;
    __syncthreads();
    if (threadIdx.x == 0) {
        double s = 0.0;
        #pragma unroll
        for (int w = 0; w < WAVES; ++w) s += sm[w];
        out[0] = (float)(0.5 * (s * (double)invB - (double)nDim));
    }
}

extern "C" void kernel_launch(void* const* d_in, const int* in_sizes, int n_in,
                              void* d_out, int out_size, void* d_ws, size_t ws_size,
                              hipStream_t stream)
{
    const float4* mu1 = (const float4*)d_in[0];
    const float4* mu2 = (const float4*)d_in[1];
    const float4* v1  = (const float4*)d_in[2];
    const float4* v2  = (const float4*)d_in[3];

    const long long total = (long long)in_sizes[0];   // B*N = 16384*1024
    const int n4 = (int)(total / 4);
    const int B = 16384;
    const int N = 1024;

    float* partial = (float*)d_ws;
    float* out = (float*)d_out;

    kl_partial_kernel<<<BLOCKS, THREADS, 0, stream>>>(mu1, mu2, v1, v2, partial, n4);
    kl_final_kernel<<<1, THREADS, 0, stream>>>(partial, out, BLOCKS,
                                               1.0f / (float)B, (float)N);
}

// Round 3
// 241.155 us; speedup vs baseline: 1.0008x; 1.0008x over previous
//
#include <hip/hip_runtime.h>

#define THREADS 256
#define ITER    4                 // float4 per thread per array
#define BLOCKS  4096              // 4096*256*4 = 4,194,304 float4 = 16,777,216 floats
#define WAVES   (THREADS / 64)

// f(i) = log(v2) - log(v1) + v1/v2 + (mu2-mu1)^2/v2
//      = t - log(t) + d*d*r      with r = 1/v2, t = v1*r
__global__ __launch_bounds__(THREADS, 4) void kl_partial_kernel(
    const float4* __restrict__ mu1, const float4* __restrict__ mu2,
    const float4* __restrict__ v1,  const float4* __restrict__ v2,
    float* __restrict__ partial, int n4)
{
    const int base = blockIdx.x * (THREADS * ITER) + threadIdx.x;

    float4 a[ITER], b[ITER], x1[ITER], x2[ITER];

    // Issue ALL 16 global_load_dwordx4 before any consumption.
    #pragma unroll
    for (int j = 0; j < ITER; ++j) {
        const int i = base + j * THREADS;
        x2[j] = v2[i];
        x1[j] = v1[i];
        a[j]  = mu1[i];
        b[j]  = mu2[i];
    }
    // Hard scheduling fence: nothing may cross. Loads stay batched above,
    // keeping ~16 VMEM ops in flight per wave (the compiler sank them in R2,
    // VGPR_Count=32 -> ~0.3 outstanding loads/wave).
    __builtin_amdgcn_sched_barrier(0);

    float acc0 = 0.0f, acc1 = 0.0f;

    #pragma unroll
    for (int j = 0; j < ITER; ++j) {
        {
            float r = __builtin_amdgcn_rcpf(x2[j].x);
            float t = x1[j].x * r;
            float d = b[j].x - a[j].x;
            acc0 += (t - __logf(t)) + d * d * r;
        }
        {
            float r = __builtin_amdgcn_rcpf(x2[j].y);
            float t = x1[j].y * r;
            float d = b[j].y - a[j].y;
            acc1 += (t - __logf(t)) + d * d * r;
        }
        {
            float r = __builtin_amdgcn_rcpf(x2[j].z);
            float t = x1[j].z * r;
            float d = b[j].z - a[j].z;
            acc0 += (t - __logf(t)) + d * d * r;
        }
        {
            float r = __builtin_amdgcn_rcpf(x2[j].w);
            float t = x1[j].w * r;
            float d = b[j].w - a[j].w;
            acc1 += (t - __logf(t)) + d * d * r;
        }
    }

    float acc = acc0 + acc1;

    // wave-level reduce (64 lanes)
    #pragma unroll
    for (int off = 32; off > 0; off >>= 1)
        acc += __shfl_down(acc, off, 64);

    __shared__ float sm[WAVES];
    const int lane = threadIdx.x & 63;
    const int wave = threadIdx.x >> 6;
    if (lane == 0) sm[wave] = acc;
    __syncthreads();
    if (threadIdx.x == 0) {
        float s = 0.0f;
        #pragma unroll
        for (int w = 0; w < WAVES; ++w) s += sm[w];
        partial[blockIdx.x] = s;
    }
}

// Reduce per-block partials (double accumulation): out = 0.5*(S/B - N)
__global__ __launch_bounds__(THREADS) void kl_final_kernel(
    const float* __restrict__ partial, float* __restrict__ out,
    int nblocks, float invB, float nDim)
{
    double acc = 0.0;
    for (int i = threadIdx.x; i < nblocks; i += THREADS)
        acc += (double)partial[i];

    #pragma unroll
    for (int off = 32; off > 0; off >>= 1)
        acc += __shfl_down(acc, off, 64);

    __shared__ double sm[WAVES];
    const int lane = threadIdx.x & 63;
    const int wave = threadIdx.x >> 6;
    if (lane == 0) sm[wave] = acc;
    __syncthreads();
    if (threadIdx.x == 0) {
        double s = 0.0;
        #pragma unroll
        for (int w = 0; w < WAVES; ++w) s += sm[w];
        out[0] = (float)(0.5 * (s * (double)invB - (double)nDim));
    }
}

extern "C" void kernel_launch(void* const* d_in, const int* in_sizes, int n_in,
                              void* d_out, int out_size, void* d_ws, size_t ws_size,
                              hipStream_t stream)
{
    const float4* mu1 = (const float4*)d_in[0];
    const float4* mu2 = (const float4*)d_in[1];
    const float4* v1  = (const float4*)d_in[2];
    const float4* v2  = (const float4*)d_in[3];

    const long long total = (long long)in_sizes[0];   // B*N = 16384*1024
    const int n4 = (int)(total / 4);
    const int B = 16384;
    const int N = 1024;

    float* partial = (float*)d_ws;
    float* out = (float*)d_out;

    kl_partial_kernel<<<BLOCKS, THREADS, 0, stream>>>(mu1, mu2, v1, v2, partial, n4);
    kl_final_kernel<<<1, THREADS, 0, stream>>>(partial, out, BLOCKS,
                                               1.0f / (float)B, (float)N);
}

// Round 5
// 214.173 us; speedup vs baseline: 1.1269x; 1.1260x over previous
//
#include <hip/hip_runtime.h>

#define THREADS 256
#define ITER    4                 // float4 per thread per array
#define BLOCKS  4096              // 4096*256*4 = 4,194,304 float4 = 16,777,216 floats
#define WAVES   (THREADS / 64)

typedef float f4 __attribute__((ext_vector_type(4)));  // native vector: nt-load OK

// f(i) = log(v2) - log(v1) + v1/v2 + (mu2-mu1)^2/v2
//      = t - log(t) + d*d*r      with r = 1/v2, t = v1*r
// R1-R3: structure-invariant 2.8 TB/s read rate (grid-stride / flat / fenced
// batch all ~95us). This round tests the cache-policy axis: nt loads.
__global__ __launch_bounds__(THREADS) void kl_partial_kernel(
    const f4* __restrict__ mu1, const f4* __restrict__ mu2,
    const f4* __restrict__ v1,  const f4* __restrict__ v2,
    float* __restrict__ partial, int n4)
{
    const int base = blockIdx.x * (THREADS * ITER) + threadIdx.x;

    float acc0 = 0.0f, acc1 = 0.0f;

    #pragma unroll
    for (int j = 0; j < ITER; ++j) {
        const int i = base + j * THREADS;
        f4 s2 = __builtin_nontemporal_load(&v2[i]);
        f4 s1 = __builtin_nontemporal_load(&v1[i]);
        f4 a  = __builtin_nontemporal_load(&mu1[i]);
        f4 b  = __builtin_nontemporal_load(&mu2[i]);

        {
            float r = __builtin_amdgcn_rcpf(s2.x);
            float t = s1.x * r;
            float d = b.x - a.x;
            acc0 += (t - __logf(t)) + d * d * r;
        }
        {
            float r = __builtin_amdgcn_rcpf(s2.y);
            float t = s1.y * r;
            float d = b.y - a.y;
            acc1 += (t - __logf(t)) + d * d * r;
        }
        {
            float r = __builtin_amdgcn_rcpf(s2.z);
            float t = s1.z * r;
            float d = b.z - a.z;
            acc0 += (t - __logf(t)) + d * d * r;
        }
        {
            float r = __builtin_amdgcn_rcpf(s2.w);
            float t = s1.w * r;
            float d = b.w - a.w;
            acc1 += (t - __logf(t)) + d * d * r;
        }
    }

    float acc = acc0 + acc1;

    // wave-level reduce (64 lanes)
    #pragma unroll
    for (int off = 32; off > 0; off >>= 1)
        acc += __shfl_down(acc, off, 64);

    __shared__ float sm[WAVES];
    const int lane = threadIdx.x & 63;
    const int wave = threadIdx.x >> 6;
    if (lane == 0) sm[wave] = acc;
    __syncthreads();
    if (threadIdx.x == 0) {
        float s = 0.0f;
        #pragma unroll
        for (int w = 0; w < WAVES; ++w) s += sm[w];
        partial[blockIdx.x] = s;
    }
}

// Reduce per-block partials (double accumulation): out = 0.5*(S/B - N)
__global__ __launch_bounds__(THREADS) void kl_final_kernel(
    const float* __restrict__ partial, float* __restrict__ out,
    int nblocks, float invB, float nDim)
{
    double acc = 0.0;
    for (int i = threadIdx.x; i < nblocks; i += THREADS)
        acc += (double)partial[i];

    #pragma unroll
    for (int off = 32; off > 0; off >>= 1)
        acc += __shfl_down(acc, off, 64);

    __shared__ double sm[WAVES];
    const int lane = threadIdx.x & 63;
    const int wave = threadIdx.x >> 6;
    if (lane == 0) sm[wave] = acc;
    __syncthreads();
    if (threadIdx.x == 0) {
        double s = 0.0;
        #pragma unroll
        for (int w = 0; w < WAVES; ++w) s += sm[w];
        out[0] = (float)(0.5 * (s * (double)invB - (double)nDim));
    }
}

extern "C" void kernel_launch(void* const* d_in, const int* in_sizes, int n_in,
                              void* d_out, int out_size, void* d_ws, size_t ws_size,
                              hipStream_t stream)
{
    const f4* mu1 = (const f4*)d_in[0];
    const f4* mu2 = (const f4*)d_in[1];
    const f4* v1  = (const f4*)d_in[2];
    const f4* v2  = (const f4*)d_in[3];

    const long long total = (long long)in_sizes[0];   // B*N = 16384*1024
    const int n4 = (int)(total / 4);
    const int B = 16384;
    const int N = 1024;

    float* partial = (float*)d_ws;
    float* out = (float*)d_out;

    kl_partial_kernel<<<BLOCKS, THREADS, 0, stream>>>(mu1, mu2, v1, v2, partial, n4);
    kl_final_kernel<<<1, THREADS, 0, stream>>>(partial, out, BLOCKS,
                                               1.0f / (float)B, (float)N);
}

// Round 6
// 211.088 us; speedup vs baseline: 1.1434x; 1.0146x over previous
//
#include <hip/hip_runtime.h>

#define THREADS 256
#define ITER    8                 // float4 per thread per array
#define BLOCKS  2048              // 2048*256*8 = 4,194,304 float4 = 16,777,216 floats
#define WAVES   (THREADS / 64)

typedef float f4 __attribute__((ext_vector_type(4)));  // native vector: nt-load OK

// f(i) = log(v2) - log(v1) + v1/v2 + (mu2-mu1)^2/v2
//      = t - log(t) + d*d*r      with r = 1/v2, t = v1*r
// R5: nontemporal loads broke the default-cache-policy ceiling (95 -> 47.5us,
// 5.65 TB/s effective). R6: halve block count, double per-thread work to trim
// epilogue/launch overhead toward the 42.6us copy-ceiling floor.
__global__ __launch_bounds__(THREADS) void kl_partial_kernel(
    const f4* __restrict__ mu1, const f4* __restrict__ mu2,
    const f4* __restrict__ v1,  const f4* __restrict__ v2,
    float* __restrict__ partial, int n4)
{
    const int base = blockIdx.x * (THREADS * ITER) + threadIdx.x;

    float acc0 = 0.0f, acc1 = 0.0f;

    #pragma unroll
    for (int j = 0; j < ITER; ++j) {
        const int i = base + j * THREADS;
        f4 s2 = __builtin_nontemporal_load(&v2[i]);
        f4 s1 = __builtin_nontemporal_load(&v1[i]);
        f4 a  = __builtin_nontemporal_load(&mu1[i]);
        f4 b  = __builtin_nontemporal_load(&mu2[i]);

        {
            float r = __builtin_amdgcn_rcpf(s2.x);
            float t = s1.x * r;
            float d = b.x - a.x;
            acc0 += (t - __logf(t)) + d * d * r;
        }
        {
            float r = __builtin_amdgcn_rcpf(s2.y);
            float t = s1.y * r;
            float d = b.y - a.y;
            acc1 += (t - __logf(t)) + d * d * r;
        }
        {
            float r = __builtin_amdgcn_rcpf(s2.z);
            float t = s1.z * r;
            float d = b.z - a.z;
            acc0 += (t - __logf(t)) + d * d * r;
        }
        {
            float r = __builtin_amdgcn_rcpf(s2.w);
            float t = s1.w * r;
            float d = b.w - a.w;
            acc1 += (t - __logf(t)) + d * d * r;
        }
    }

    float acc = acc0 + acc1;

    // wave-level reduce (64 lanes)
    #pragma unroll
    for (int off = 32; off > 0; off >>= 1)
        acc += __shfl_down(acc, off, 64);

    __shared__ float sm[WAVES];
    const int lane = threadIdx.x & 63;
    const int wave = threadIdx.x >> 6;
    if (lane == 0) sm[wave] = acc;
    __syncthreads();
    if (threadIdx.x == 0) {
        float s = 0.0f;
        #pragma unroll
        for (int w = 0; w < WAVES; ++w) s += sm[w];
        partial[blockIdx.x] = s;
    }
}

// Reduce per-block partials (double accumulation): out = 0.5*(S/B - N)
__global__ __launch_bounds__(THREADS) void kl_final_kernel(
    const float* __restrict__ partial, float* __restrict__ out,
    int nblocks, float invB, float nDim)
{
    double acc = 0.0;
    for (int i = threadIdx.x; i < nblocks; i += THREADS)
        acc += (double)partial[i];

    #pragma unroll
    for (int off = 32; off > 0; off >>= 1)
        acc += __shfl_down(acc, off, 64);

    __shared__ double sm[WAVES];
    const int lane = threadIdx.x & 63;
    const int wave = threadIdx.x >> 6;
    if (lane == 0) sm[wave] = acc;
    __syncthreads();
    if (threadIdx.x == 0) {
        double s = 0.0;
        #pragma unroll
        for (int w = 0; w < WAVES; ++w) s += sm[w];
        out[0] = (float)(0.5 * (s * (double)invB - (double)nDim));
    }
}

extern "C" void kernel_launch(void* const* d_in, const int* in_sizes, int n_in,
                              void* d_out, int out_size, void* d_ws, size_t ws_size,
                              hipStream_t stream)
{
    const f4* mu1 = (const f4*)d_in[0];
    const f4* mu2 = (const f4*)d_in[1];
    const f4* v1  = (const f4*)d_in[2];
    const f4* v2  = (const f4*)d_in[3];

    const long long total = (long long)in_sizes[0];   // B*N = 16384*1024
    const int n4 = (int)(total / 4);
    const int B = 16384;
    const int N = 1024;

    float* partial = (float*)d_ws;
    float* out = (float*)d_out;

    kl_partial_kernel<<<BLOCKS, THREADS, 0, stream>>>(mu1, mu2, v1, v2, partial, n4);
    kl_final_kernel<<<1, THREADS, 0, stream>>>(partial, out, BLOCKS,
                                               1.0f / (float)B, (float)N);
}